// Round 2
// baseline (1677.995 us; speedup 1.0000x reference)
//
#include <hip/hip_runtime.h>
#include <math.h>

// Problem constants
#define Bq 2
#define Nq 4096
#define Dq 64
#define MAXR 16          // rounds launched = supports n_eps up to 14
#define RB 8             // row-bands for column softmin partials
#define W_LOG (-8.317766166719343f)   // -log(4096) (N == M, uniform weights)
#define DQ_SCALE (4.0f / 65535.0f)    // u16 -> C dequant
#define Q_SCALE  16383.75f            // C -> u16 quant (65535/4, exact in f32)

// ---- workspace layout (float offsets) ----
#define F_XN   ((size_t)0)                               // normalized x: B*N*D
#define F_YN   (F_XN + (size_t)Bq * Nq * Dq)             // normalized y
#define F_FG   (F_YN + (size_t)Bq * Nq * Dq)             // duals: 2 copies x 4 arrays x B*N
#define F_EPS  (F_FG + (size_t)2 * 4 * Bq * Nq)          // [0..7]=ints, [8..]=eps values
#define F_MM   (F_EPS + 64)                              // minmax partials: 64 x 128
#define F_CP   (F_MM + (size_t)64 * 128)                 // col partials: B*N*RB*2
#define F_C    (F_CP + (size_t)Bq * Nq * RB * 2)         // 3 cost matrices in u16
#define GSZ    ((size_t)Bq * Nq * Nq)                    // u16 elements per matrix
#define F_TOTAL_P (F_C + 3 * GSZ / 2)                    // ~206 MB (u16 area in floats)
#define F_TOTAL_S (F_C)                                  // ~5 MB fallback footprint

// ---------------- normalize points ----------------
__global__ __launch_bounds__(256) void k_normalize(const float* __restrict__ x,
                                                   const float* __restrict__ y,
                                                   float* __restrict__ ws) {
    int gid = blockIdx.x * 256 + threadIdx.x;
    int wave = gid >> 6;                // point id across both tensors
    int lane = gid & 63;                // dim (D == 64)
    int tensor = wave / (Bq * Nq);
    int p = wave % (Bq * Nq);
    const float* src = tensor ? y : x;
    float v = src[(size_t)p * Dq + lane];
    float s = v * v;
    #pragma unroll
    for (int o = 32; o > 0; o >>= 1) s += __shfl_xor(s, o);
    float* dst = ws + (tensor ? F_YN : F_XN);
    dst[(size_t)p * Dq + lane] = v / sqrtf(s);
}

// ---------------- per-dim max/min partials (raw inputs, both clouds) ----------------
__global__ __launch_bounds__(256) void k_minmax(const float* __restrict__ x,
                                                const float* __restrict__ y,
                                                float* __restrict__ ws) {
    int d = threadIdx.x & 63, q = threadIdx.x >> 6;
    int p0 = blockIdx.x * 256;
    float mx = -INFINITY, mn = INFINITY;
    for (int p = p0 + q; p < p0 + 256; p += 4) {
        const float* src = (p < Bq * Nq) ? x : y;
        int pp = (p < Bq * Nq) ? p : p - Bq * Nq;
        float v = src[(size_t)pp * Dq + d];
        mx = fmaxf(mx, v); mn = fminf(mn, v);
    }
    __shared__ float smx[4][64], smn[4][64];
    smx[q][d] = mx; smn[q][d] = mn;
    __syncthreads();
    if (threadIdx.x < 64) {
        float a = fmaxf(fmaxf(smx[0][d], smx[1][d]), fmaxf(smx[2][d], smx[3][d]));
        float i = fminf(fminf(smn[0][d], smn[1][d]), fminf(smn[2][d], smn[3][d]));
        ws[F_MM + (size_t)blockIdx.x * 128 + d] = a;
        ws[F_MM + (size_t)blockIdx.x * 128 + 64 + d] = i;
    }
}

// ---------------- diameter + eps schedule (np.arange semantics, f64) ----------------
__global__ void k_eps(float* __restrict__ ws) {
    int d = threadIdx.x;  // 64 threads = 1 wave
    float mx = -INFINITY, mn = INFINITY;
    for (int k = 0; k < 64; k++) {
        mx = fmaxf(mx, ws[F_MM + (size_t)k * 128 + d]);
        mn = fminf(mn, ws[F_MM + (size_t)k * 128 + 64 + d]);
    }
    float r = mx - mn;
    float r2 = r * r;
    #pragma unroll
    for (int o = 32; o > 0; o >>= 1) r2 += __shfl_xor(r2, o);
    if (d == 0) {
        double dd = (double)sqrtf(r2);               // f32-rounded diameter like np
        double start = 2.0 * log(dd);                // P * log(diameter)
        double stop  = 2.0 * log(sqrt(0.1));         // P * log(BLUR)
        double step  = 2.0 * log(0.5);               // P * log(SCALING)
        double lend = ceil((stop - start) / step);
        int len = (lend <= 0.0) ? 0 : (int)lend;
        int n = len + 2;                             // len(eps_list)
        if (n > MAXR - 2) n = MAXR - 2;
        int* ei = (int*)(ws + F_EPS);
        ei[0] = n;
        float* ev = ws + F_EPS + 8;
        ev[0] = (float)(dd * dd);
        for (int i = 0; i < len && i + 1 < n - 1; i++)
            ev[1 + i] = (float)exp(start + i * step);
        ev[n - 1] = 0.1f;                            // BLUR**P
    }
}

// ---------------- cost matrices quantized u16: op0 C_xy, op1 C_xx, op2 C_yy ----------------
__global__ __launch_bounds__(256) void k_gram_q(float* __restrict__ ws) {
    int op = blockIdx.z, b = blockIdx.y;
    int tr = (blockIdx.x >> 6) << 6;
    int tc = (blockIdx.x & 63) << 6;
    const float* A  = ws + (op == 2 ? F_YN : F_XN) + (size_t)b * Nq * Dq;
    const float* Bt = ws + (op == 1 ? F_XN : F_YN) + (size_t)b * Nq * Dq;
    __shared__ float As[64][65], Bs[64][65];
    #pragma unroll
    for (int i = 0; i < 16; i++) {
        int idx = threadIdx.x + 256 * i;
        int rr = idx >> 6, cc = idx & 63;
        As[rr][cc] = A[(size_t)(tr + rr) * Dq + cc];
        Bs[rr][cc] = Bt[(size_t)(tc + rr) * Dq + cc];
    }
    __syncthreads();
    int tx = threadIdx.x & 15, ty = threadIdx.x >> 4;
    float acc[4][4] = {};
    #pragma unroll
    for (int dd = 0; dd < 64; dd++) {
        float a[4], bb[4];
        #pragma unroll
        for (int i = 0; i < 4; i++) a[i] = As[ty * 4 + i][dd];
        #pragma unroll
        for (int j = 0; j < 4; j++) bb[j] = Bs[tx * 4 + j][dd];
        #pragma unroll
        for (int i = 0; i < 4; i++)
            #pragma unroll
            for (int j = 0; j < 4; j++) acc[i][j] = fmaf(a[i], bb[j], acc[i][j]);
    }
    unsigned short* C = (unsigned short*)(ws + F_C) + (size_t)op * GSZ + (size_t)b * Nq * Nq;
    #pragma unroll
    for (int i = 0; i < 4; i++) {
        ushort4 o;
        unsigned short* po = &o.x;
        #pragma unroll
        for (int j = 0; j < 4; j++) {
            float c = 1.0f - acc[i][j];
            float Cv = fminf(c * c, 4.0f);           // clamp: |cos| can round past 1
            unsigned int u = __float2uint_rn(Cv * Q_SCALE);
            if (u > 65535u) u = 65535u;
            po[j] = (unsigned short)u;
        }
        *reinterpret_cast<ushort4*>(&C[(size_t)(tr + ty * 4 + i) * Nq + tc + tx * 4]) = o;
    }
}

// round r: mode 0 = init (r==0), 1 = damped loop (1..n_eps), 2 = final (n_eps+1)
__device__ __forceinline__ bool round_cfg(const float* ws, int r, int& mode, float& eps,
                                          float& inv_eps, int& cur, int& nxt) {
    const int* ei = (const int*)(ws + F_EPS);
    int n_eps = ei[0];
    if (r > n_eps + 1) return false;
    mode = (r == 0) ? 0 : ((r <= n_eps) ? 1 : 2);
    int eidx = (r == 0) ? 0 : ((r - 1 < n_eps - 1) ? r - 1 : n_eps - 1);
    eps = ws[F_EPS + 8 + eidx];
    inv_eps = 1.0f / eps;
    cur = r & 1; nxt = cur ^ 1;
    return true;
}

// ---------------- row softmins: op0 C_xy -> f_ba; op1 C_xx -> f_aa; op2 C_yy -> g_bb ----
__global__ __launch_bounds__(256) void k_row(float* __restrict__ ws, int r) {
    int mode, cur, nxt; float eps, inv_eps;
    if (!round_cfg(ws, r, mode, eps, inv_eps, cur, nxt)) return;

    int bid = blockIdx.x;
    int op = bid / (Bq * Nq);
    int rem = bid % (Bq * Nq);
    int b = rem >> 12, n = rem & (Nq - 1);
    const unsigned short* C = (const unsigned short*)(ws + F_C)
                              + (size_t)op * GSZ + ((size_t)b * Nq + n) * Nq;
    int arr_dual = (op == 0) ? 1 : (op == 1 ? 2 : 3);   // g_ab / f_aa / g_bb
    int arr_out  = (op == 0) ? 0 : arr_dual;            // f_ba / f_aa / g_bb
    const uint4* C4 = reinterpret_cast<const uint4*>(C);   // 8 u16 per granule
    const float4* d4 = reinterpret_cast<const float4*>(
        ws + F_FG + ((size_t)cur * 4 + arr_dual) * (Bq * Nq) + (size_t)b * Nq);

    float vs[16];
    float vmax = -INFINITY;
    #pragma unroll
    for (int k = 0; k < 2; k++) {
        int gi = threadIdx.x + 256 * k;                 // granule: cols [gi*8, gi*8+8)
        uint4 cu = C4[gi];
        float4 h0 = make_float4(0.f, 0.f, 0.f, 0.f), h1 = h0;
        if (mode != 0) { h0 = d4[gi * 2]; h1 = d4[gi * 2 + 1]; }
        float hv[8] = {h0.x, h0.y, h0.z, h0.w, h1.x, h1.y, h1.z, h1.w};
        unsigned int uw[4] = {cu.x, cu.y, cu.z, cu.w};
        #pragma unroll
        for (int j = 0; j < 8; j++) {
            unsigned int u = (uw[j >> 1] >> ((j & 1) * 16)) & 0xffffu;
            float Cv = (float)u * DQ_SCALE;
            float v = W_LOG + (hv[j] - Cv) * inv_eps;
            vs[k * 8 + j] = v;
            vmax = fmaxf(vmax, v);
        }
    }
    #pragma unroll
    for (int o = 32; o > 0; o >>= 1) vmax = fmaxf(vmax, __shfl_xor(vmax, o));
    __shared__ float red[4], red2[4];
    int wid = threadIdx.x >> 6;
    if ((threadIdx.x & 63) == 0) red[wid] = vmax;
    __syncthreads();
    float bm = fmaxf(fmaxf(red[0], red[1]), fmaxf(red[2], red[3]));
    float s = 0.f;
    #pragma unroll
    for (int k = 0; k < 16; k++) s += expf(vs[k] - bm);
    #pragma unroll
    for (int o = 32; o > 0; o >>= 1) s += __shfl_xor(s, o);
    if ((threadIdx.x & 63) == 0) red2[wid] = s;
    __syncthreads();
    if (threadIdx.x == 0) {
        float st = red2[0] + red2[1] + red2[2] + red2[3];
        float ft = -eps * (bm + logf(st));
        float* outp = ws + F_FG + ((size_t)nxt * 4 + arr_out) * (Bq * Nq) + (size_t)b * Nq;
        const float* oldp = ws + F_FG + ((size_t)cur * 4 + arr_out) * (Bq * Nq) + (size_t)b * Nq;
        outp[n] = (mode == 1) ? 0.5f * (oldp[n] + ft) : ft;
    }
}

// ---------------- column softmin of C_xy (for g_ab): partial per row-band ----------------
__global__ __launch_bounds__(256) void k_colpart(float* __restrict__ ws, int r) {
    int mode, cur, nxt; float eps, inv_eps;
    if (!round_cfg(ws, r, mode, eps, inv_eps, cur, nxt)) return;

    int bid = blockIdx.x;                 // B * 64 colblocks * RB bands
    int band = bid & (RB - 1);
    int cb = (bid >> 3) & 63;
    int b = bid >> 9;
    int c = threadIdx.x & 63, q = threadIdx.x >> 6;
    int m = cb * 64 + c;
    const unsigned short* C = (const unsigned short*)(ws + F_C) + (size_t)b * Nq * Nq; // C_xy
    const float* fba = ws + F_FG + ((size_t)cur * 4 + 0) * (Bq * Nq) + (size_t)b * Nq;

    float mx = -INFINITY, s = 0.f;
    int n0 = band * (Nq / RB);
    for (int n = n0 + q; n < n0 + Nq / RB; n += 4) {
        float Cv = (float)C[(size_t)n * Nq + m] * DQ_SCALE;
        float h = (mode == 0) ? 0.f : fba[n] * inv_eps;  // wave-uniform n -> scalar load
        float v = W_LOG + h - Cv * inv_eps;
        float nm = fmaxf(mx, v);
        s = s * expf(mx - nm) + expf(v - nm);
        mx = nm;
    }
    __shared__ float sm[4][64], ss[4][64];
    sm[q][c] = mx; ss[q][c] = s;
    __syncthreads();
    if (threadIdx.x < 64) {
        float M = fmaxf(fmaxf(sm[0][c], sm[1][c]), fmaxf(sm[2][c], sm[3][c]));
        float S = ss[0][c] * expf(sm[0][c] - M) + ss[1][c] * expf(sm[1][c] - M)
                + ss[2][c] * expf(sm[2][c] - M) + ss[3][c] * expf(sm[3][c] - M);
        size_t o = F_CP + (((size_t)b * Nq + cb * 64 + c) * RB + band) * 2;
        ws[o] = M; ws[o + 1] = S;
    }
}

__global__ __launch_bounds__(256) void k_colcomb(float* __restrict__ ws, int r) {
    int mode, cur, nxt; float eps, inv_eps;
    if (!round_cfg(ws, r, mode, eps, inv_eps, cur, nxt)) return;
    int idx = blockIdx.x * 256 + threadIdx.x;
    if (idx >= Bq * Nq) return;
    int b = idx >> 12, m = idx & (Nq - 1);
    size_t o = F_CP + (((size_t)b * Nq + m) * RB) * 2;
    float M = -INFINITY;
    #pragma unroll
    for (int k = 0; k < RB; k++) M = fmaxf(M, ws[o + 2 * k]);
    float S = 0.f;
    #pragma unroll
    for (int k = 0; k < RB; k++) S += ws[o + 2 * k + 1] * expf(ws[o + 2 * k] - M);
    float gt = -eps * (M + logf(S));
    float* outp = ws + F_FG + ((size_t)nxt * 4 + 1) * (Bq * Nq) + (size_t)b * Nq;
    const float* oldp = ws + F_FG + ((size_t)cur * 4 + 1) * (Bq * Nq) + (size_t)b * Nq;
    outp[m] = (mode == 1) ? 0.5f * (oldp[m] + gt) : gt;
}

// ---------------- fallback: fused recompute + row softmin (small ws) ----------------
// op0: C_xy rows w/ dual g_ab -> f_ba   (A=X, B=Y)
// op1: C_yx rows w/ dual f_ba -> g_ab   (A=Y, B=X)
// op2: C_xx rows w/ dual f_aa -> f_aa   (A=X, B=X)
// op3: C_yy rows w/ dual g_bb -> g_bb   (A=Y, B=Y)
__global__ __launch_bounds__(256) void k_fused(float* __restrict__ ws, int r) {
    int mode, cur, nxt; float eps, inv_eps;
    if (!round_cfg(ws, r, mode, eps, inv_eps, cur, nxt)) return;
    int op = blockIdx.z, b = blockIdx.y;
    int tr = blockIdx.x * 64;
    const float* A  = ws + ((op == 1 || op == 3) ? F_YN : F_XN) + (size_t)b * Nq * Dq;
    const float* Bp = ws + ((op == 0 || op == 3) ? F_YN : F_XN) + (size_t)b * Nq * Dq;
    int dual_arr = (op == 0) ? 1 : (op == 1) ? 0 : (op == 2) ? 2 : 3;
    int out_arr  = (op == 0) ? 0 : (op == 1) ? 1 : (op == 2) ? 2 : 3;
    const float* hdual = ws + F_FG + ((size_t)cur * 4 + dual_arr) * (Bq * Nq) + (size_t)b * Nq;

    __shared__ float As[64][65], Bs[64][65];
    #pragma unroll
    for (int i = 0; i < 16; i++) {
        int idx = threadIdx.x + 256 * i;
        As[idx >> 6][idx & 63] = A[(size_t)(tr + (idx >> 6)) * Dq + (idx & 63)];
    }
    int tx = threadIdx.x & 15, ty = threadIdx.x >> 4;
    float m_i[4], s_i[4];
    #pragma unroll
    for (int i = 0; i < 4; i++) { m_i[i] = -INFINITY; s_i[i] = 0.f; }

    for (int tc = 0; tc < Nq; tc += 64) {
        __syncthreads();
        #pragma unroll
        for (int i = 0; i < 16; i++) {
            int idx = threadIdx.x + 256 * i;
            Bs[idx >> 6][idx & 63] = Bp[(size_t)(tc + (idx >> 6)) * Dq + (idx & 63)];
        }
        __syncthreads();
        float acc[4][4] = {};
        #pragma unroll
        for (int dd = 0; dd < 64; dd++) {
            float a[4], bb[4];
            #pragma unroll
            for (int i = 0; i < 4; i++) a[i] = As[ty * 4 + i][dd];
            #pragma unroll
            for (int j = 0; j < 4; j++) bb[j] = Bs[tx * 4 + j][dd];
            #pragma unroll
            for (int i = 0; i < 4; i++)
                #pragma unroll
                for (int j = 0; j < 4; j++) acc[i][j] = fmaf(a[i], bb[j], acc[i][j]);
        }
        float hv[4];
        #pragma unroll
        for (int j = 0; j < 4; j++)
            hv[j] = (mode == 0) ? 0.f : hdual[tc + tx * 4 + j];
        #pragma unroll
        for (int i = 0; i < 4; i++) {
            float v[4], tm = -INFINITY;
            #pragma unroll
            for (int j = 0; j < 4; j++) {
                float c = 1.0f - acc[i][j];
                v[j] = W_LOG + (hv[j] - c * c) * inv_eps;
                tm = fmaxf(tm, v[j]);
            }
            float nm = fmaxf(m_i[i], tm);
            float add = 0.f;
            #pragma unroll
            for (int j = 0; j < 4; j++) add += expf(v[j] - nm);
            s_i[i] = s_i[i] * expf(m_i[i] - nm) + add;
            m_i[i] = nm;
        }
    }
    // reduce (m,s) across the 16 tx lanes (same wave: tx = low 4 bits of lane)
    #pragma unroll
    for (int o = 1; o < 16; o <<= 1) {
        #pragma unroll
        for (int i = 0; i < 4; i++) {
            float om = __shfl_xor(m_i[i], o);
            float os = __shfl_xor(s_i[i], o);
            float M = fmaxf(m_i[i], om);
            s_i[i] = s_i[i] * expf(m_i[i] - M) + os * expf(om - M);
            m_i[i] = M;
        }
    }
    if (tx == 0) {
        float* outp = ws + F_FG + ((size_t)nxt * 4 + out_arr) * (Bq * Nq) + (size_t)b * Nq;
        const float* oldp = ws + F_FG + ((size_t)cur * 4 + out_arr) * (Bq * Nq) + (size_t)b * Nq;
        #pragma unroll
        for (int i = 0; i < 4; i++) {
            int n = tr + ty * 4 + i;
            float ft = -eps * (m_i[i] + logf(s_i[i]));
            outp[n] = (mode == 1) ? 0.5f * (oldp[n] + ft) : ft;
        }
    }
}

// ---------------- final cost ----------------
__global__ __launch_bounds__(256) void k_final(const float* __restrict__ ws,
                                               float* __restrict__ out) {
    const int* ei = (const int*)(ws + F_EPS);
    int n_eps = ei[0];
    int fin = n_eps & 1;                  // copy written by round n_eps+1
    int b = blockIdx.x;
    const float* fba = ws + F_FG + ((size_t)fin * 4 + 0) * (Bq * Nq) + (size_t)b * Nq;
    const float* gab = ws + F_FG + ((size_t)fin * 4 + 1) * (Bq * Nq) + (size_t)b * Nq;
    const float* faa = ws + F_FG + ((size_t)fin * 4 + 2) * (Bq * Nq) + (size_t)b * Nq;
    const float* gbb = ws + F_FG + ((size_t)fin * 4 + 3) * (Bq * Nq) + (size_t)b * Nq;
    float s = 0.f;
    for (int n = threadIdx.x; n < Nq; n += 256)
        s += (fba[n] - faa[n]) + (gab[n] - gbb[n]);
    #pragma unroll
    for (int o = 32; o > 0; o >>= 1) s += __shfl_xor(s, o);
    __shared__ float red[4];
    if ((threadIdx.x & 63) == 0) red[threadIdx.x >> 6] = s;
    __syncthreads();
    if (threadIdx.x == 0)
        out[b] = (red[0] + red[1] + red[2] + red[3]) * (1.0f / Nq);
}

// sentinel: ws too small even for the fallback
__global__ void k_sentinel(float* out, int n) {
    if ((int)threadIdx.x < n) out[threadIdx.x] = 2.0e9f;
}

extern "C" void kernel_launch(void* const* d_in, const int* in_sizes, int n_in,
                              void* d_out, int out_size, void* d_ws, size_t ws_size,
                              hipStream_t stream) {
    const float* x = (const float*)d_in[0];
    const float* y = (const float*)d_in[1];
    float* out = (float*)d_out;
    float* ws = (float*)d_ws;

    bool big   = ws_size >= F_TOTAL_P * sizeof(float);   // ~206 MB
    bool small = ws_size >= F_TOTAL_S * sizeof(float);   // ~5 MB

    if (!small) {
        k_sentinel<<<1, 64, 0, stream>>>(out, out_size);
        return;
    }

    k_normalize<<<(2 * Bq * Nq * 64) / 256, 256, 0, stream>>>(x, y, ws);
    k_minmax<<<64, 256, 0, stream>>>(x, y, ws);
    k_eps<<<1, 64, 0, stream>>>(ws);

    if (big) {
        k_gram_q<<<dim3(4096, Bq, 3), 256, 0, stream>>>(ws);
        for (int r = 0; r < MAXR; r++) {
            k_row<<<3 * Bq * Nq, 256, 0, stream>>>(ws, r);
            k_colpart<<<Bq * 64 * RB, 256, 0, stream>>>(ws, r);
            k_colcomb<<<(Bq * Nq + 255) / 256, 256, 0, stream>>>(ws, r);
        }
    } else {
        for (int r = 0; r < MAXR; r++) {
            k_fused<<<dim3(Nq / 64, Bq, 4), 256, 0, stream>>>(ws, r);
        }
    }

    k_final<<<Bq, 256, 0, stream>>>(ws, out);
}

// Round 3
// 1427.775 us; speedup vs baseline: 1.1753x; 1.1753x over previous
//
#include <hip/hip_runtime.h>
#include <math.h>

// Problem constants
#define Bq 2
#define Nq 4096
#define Dq 64
#define MAXR 14          // rounds launched = supports n_eps up to 12 (diameter <= ~187)
#define RB 8             // row-bands for column softmin partials
#define W_LOG (-8.317766166719343f)   // -log(4096) (N == M, uniform weights)
#define LOG2E 1.4426950408889634f
#define LN2   0.6931471805599453f
#define DQ_SCALE (4.0f / 65535.0f)    // u16 -> C dequant
#define Q_SCALE  16383.75f            // C -> u16 quant (65535/4, exact in f32)

// ---- workspace layout (float offsets) ----
#define F_XN   ((size_t)0)                               // normalized x f32: B*N*D
#define F_YN   (F_XN + (size_t)Bq * Nq * Dq)             // normalized y f32
#define F_XH   (F_YN + (size_t)Bq * Nq * Dq)             // bf16 hi(x): B*N*D u16
#define F_XL   (F_XH + (size_t)Bq * Nq * Dq / 2)         // bf16 lo(x)
#define F_YH   (F_XL + (size_t)Bq * Nq * Dq / 2)
#define F_YL   (F_YH + (size_t)Bq * Nq * Dq / 2)
#define F_FG   (F_YL + (size_t)Bq * Nq * Dq / 2)         // duals: 2 copies x 4 arrays x B*N
#define F_EPS  (F_FG + (size_t)2 * 4 * Bq * Nq)          // [0..7]=ints, [8..]=eps values
#define F_MM   (F_EPS + 64)                              // minmax partials: 64 x 128
#define F_CP   (F_MM + (size_t)64 * 128)                 // col partials: B*N*RB*2
#define F_C    (F_CP + (size_t)Bq * Nq * RB * 2)         // 3 cost matrices in u16
#define GSZ    ((size_t)Bq * Nq * Nq)                    // u16 elements per matrix
#define F_TOTAL_P (F_C + 3 * GSZ / 2)                    // ~210 MB
#define F_TOTAL_S (F_C)                                  // ~9.5 MB fallback footprint

typedef short short8v __attribute__((ext_vector_type(8)));   // 8 bf16 bits (4 VGPRs)
typedef float f32x4 __attribute__((ext_vector_type(4)));

__device__ __forceinline__ unsigned short f2bf(float f) {
    unsigned u = __float_as_uint(f);
    unsigned r = (u + 0x7fffu + ((u >> 16) & 1u)) >> 16;   // RNE
    return (unsigned short)r;
}
__device__ __forceinline__ float bf2f(unsigned short b) {
    return __uint_as_float(((unsigned)b) << 16);
}

// ---------------- normalize points (+ split-bf16 copies) ----------------
__global__ __launch_bounds__(256) void k_normalize(const float* __restrict__ x,
                                                   const float* __restrict__ y,
                                                   float* __restrict__ ws) {
    int gid = blockIdx.x * 256 + threadIdx.x;
    int wave = gid >> 6;                // point id across both tensors
    int lane = gid & 63;                // dim (D == 64)
    int tensor = wave / (Bq * Nq);
    int p = wave % (Bq * Nq);
    const float* src = tensor ? y : x;
    float v = src[(size_t)p * Dq + lane];
    float s = v * v;
    #pragma unroll
    for (int o = 32; o > 0; o >>= 1) s += __shfl_xor(s, o);
    float vn = v / sqrtf(s);
    float* dst = ws + (tensor ? F_YN : F_XN);
    dst[(size_t)p * Dq + lane] = vn;
    unsigned short hb = f2bf(vn);
    float lo = vn - bf2f(hb);
    unsigned short lb = f2bf(lo);
    unsigned short* dh = (unsigned short*)(ws + (tensor ? F_YH : F_XH));
    unsigned short* dl = (unsigned short*)(ws + (tensor ? F_YL : F_XL));
    dh[(size_t)p * Dq + lane] = hb;
    dl[(size_t)p * Dq + lane] = lb;
}

// ---------------- per-dim max/min partials (raw inputs, both clouds) ----------------
__global__ __launch_bounds__(256) void k_minmax(const float* __restrict__ x,
                                                const float* __restrict__ y,
                                                float* __restrict__ ws) {
    int d = threadIdx.x & 63, q = threadIdx.x >> 6;
    int p0 = blockIdx.x * 256;
    float mx = -INFINITY, mn = INFINITY;
    for (int p = p0 + q; p < p0 + 256; p += 4) {
        const float* src = (p < Bq * Nq) ? x : y;
        int pp = (p < Bq * Nq) ? p : p - Bq * Nq;
        float v = src[(size_t)pp * Dq + d];
        mx = fmaxf(mx, v); mn = fminf(mn, v);
    }
    __shared__ float smx[4][64], smn[4][64];
    smx[q][d] = mx; smn[q][d] = mn;
    __syncthreads();
    if (threadIdx.x < 64) {
        float a = fmaxf(fmaxf(smx[0][d], smx[1][d]), fmaxf(smx[2][d], smx[3][d]));
        float i = fminf(fminf(smn[0][d], smn[1][d]), fminf(smn[2][d], smn[3][d]));
        ws[F_MM + (size_t)blockIdx.x * 128 + d] = a;
        ws[F_MM + (size_t)blockIdx.x * 128 + 64 + d] = i;
    }
}

// ---------------- diameter + eps schedule (np.arange semantics, f64) ----------------
__global__ void k_eps(float* __restrict__ ws) {
    int d = threadIdx.x;  // 64 threads = 1 wave
    float mx = -INFINITY, mn = INFINITY;
    for (int k = 0; k < 64; k++) {
        mx = fmaxf(mx, ws[F_MM + (size_t)k * 128 + d]);
        mn = fminf(mn, ws[F_MM + (size_t)k * 128 + 64 + d]);
    }
    float r = mx - mn;
    float r2 = r * r;
    #pragma unroll
    for (int o = 32; o > 0; o >>= 1) r2 += __shfl_xor(r2, o);
    if (d == 0) {
        double dd = (double)sqrtf(r2);               // f32-rounded diameter like np
        double start = 2.0 * log(dd);                // P * log(diameter)
        double stop  = 2.0 * log(sqrt(0.1));         // P * log(BLUR)
        double step  = 2.0 * log(0.5);               // P * log(SCALING)
        double lend = ceil((stop - start) / step);
        int len = (lend <= 0.0) ? 0 : (int)lend;
        int n = len + 2;                             // len(eps_list)
        if (n > MAXR - 2) n = MAXR - 2;
        int* ei = (int*)(ws + F_EPS);
        ei[0] = n;
        float* ev = ws + F_EPS + 8;
        ev[0] = (float)(dd * dd);
        for (int i = 0; i < len && i + 1 < n - 1; i++)
            ev[1 + i] = (float)exp(start + i * step);
        ev[n - 1] = 0.1f;                            // BLUR**P
    }
}

// ------- cost matrices via split-bf16 MFMA: op0 C_xy, op1 C_xx, op2 C_yy -> u16 -------
// tile: 16 rows x 256 cols per block; wave w covers cols [w*64, w*64+64)
__global__ __launch_bounds__(256) void k_gram_mfma(float* __restrict__ ws) {
    int op = blockIdx.z, b = blockIdx.y;
    int tr = (blockIdx.x & 255) * 16;
    int tc = (blockIdx.x >> 8) * 256;
    const unsigned short* AH = (const unsigned short*)(ws + (op == 2 ? F_YH : F_XH)) + (size_t)b * Nq * Dq;
    const unsigned short* AL = (const unsigned short*)(ws + (op == 2 ? F_YL : F_XL)) + (size_t)b * Nq * Dq;
    const unsigned short* BH = (const unsigned short*)(ws + (op == 1 ? F_XH : F_YH)) + (size_t)b * Nq * Dq;
    const unsigned short* BL = (const unsigned short*)(ws + (op == 1 ? F_XL : F_YL)) + (size_t)b * Nq * Dq;
    int w = threadIdx.x >> 6, lane = threadIdx.x & 63;
    int m = lane & 15, kb = lane >> 4;          // A/B frag: row/col = m, k-chunk = kb*8 (+32 per step)

    size_t arow = (size_t)(tr + m) * Dq + kb * 8;
    short8v aH0 = *(const short8v*)(AH + arow);
    short8v aH1 = *(const short8v*)(AH + arow + 32);
    short8v aL0 = *(const short8v*)(AL + arow);
    short8v aL1 = *(const short8v*)(AL + arow + 32);

    __shared__ float lds[16][260];              // 260: 16B-aligned rows, 2-way max bank alias
    #pragma unroll
    for (int cb = 0; cb < 4; cb++) {
        int col = tc + w * 64 + cb * 16 + m;
        size_t brow = (size_t)col * Dq + kb * 8;
        short8v bH0 = *(const short8v*)(BH + brow);
        short8v bH1 = *(const short8v*)(BH + brow + 32);
        short8v bL0 = *(const short8v*)(BL + brow);
        short8v bL1 = *(const short8v*)(BL + brow + 32);
        f32x4 acc = {0.f, 0.f, 0.f, 0.f};
        acc = __builtin_amdgcn_mfma_f32_16x16x32_bf16(aH0, bH0, acc, 0, 0, 0);
        acc = __builtin_amdgcn_mfma_f32_16x16x32_bf16(aH1, bH1, acc, 0, 0, 0);
        acc = __builtin_amdgcn_mfma_f32_16x16x32_bf16(aL0, bH0, acc, 0, 0, 0);
        acc = __builtin_amdgcn_mfma_f32_16x16x32_bf16(aL1, bH1, acc, 0, 0, 0);
        acc = __builtin_amdgcn_mfma_f32_16x16x32_bf16(aH0, bL0, acc, 0, 0, 0);
        acc = __builtin_amdgcn_mfma_f32_16x16x32_bf16(aH1, bL1, acc, 0, 0, 0);
        // C/D layout: col = lane&15, row = kb*4 + reg  [m89-verified]
        #pragma unroll
        for (int rr = 0; rr < 4; rr++)
            lds[kb * 4 + rr][w * 64 + cb * 16 + m] = acc[rr];
    }
    __syncthreads();
    // quantize + coalesced u16 store
    unsigned short* C = (unsigned short*)(ws + F_C) + (size_t)op * GSZ + (size_t)b * Nq * Nq;
    #pragma unroll
    for (int i = 0; i < 2; i++) {
        int c = threadIdx.x + 256 * i;          // 0..511 chunks of 8
        int row = c >> 5, off = (c & 31) * 8;
        uint4 pk;
        unsigned int* pw = &pk.x;
        #pragma unroll
        for (int j = 0; j < 4; j++) {
            float g0 = lds[row][off + 2 * j];
            float g1 = lds[row][off + 2 * j + 1];
            float c0 = 1.0f - g0, c1 = 1.0f - g1;
            unsigned u0 = __float2uint_rn(fminf(c0 * c0, 4.0f) * Q_SCALE);
            unsigned u1 = __float2uint_rn(fminf(c1 * c1, 4.0f) * Q_SCALE);
            if (u0 > 65535u) u0 = 65535u;
            if (u1 > 65535u) u1 = 65535u;
            pw[j] = u0 | (u1 << 16);
        }
        *reinterpret_cast<uint4*>(&C[(size_t)(tr + row) * Nq + tc + off]) = pk;
    }
}

// round r: mode 0 = init (r==0), 1 = damped loop (1..n_eps), 2 = final (n_eps+1)
__device__ __forceinline__ bool round_cfg(const float* ws, int r, int& mode, float& eps,
                                          float& inv_eps, int& cur, int& nxt) {
    const int* ei = (const int*)(ws + F_EPS);
    int n_eps = ei[0];
    if (r > n_eps + 1) return false;
    mode = (r == 0) ? 0 : ((r <= n_eps) ? 1 : 2);
    int eidx = (r == 0) ? 0 : ((r - 1 < n_eps - 1) ? r - 1 : n_eps - 1);
    eps = ws[F_EPS + 8 + eidx];
    inv_eps = 1.0f / eps;
    cur = r & 1; nxt = cur ^ 1;
    return true;
}

// -------- fused per-round kernel: row softmins (3 ops) + column partials --------
// blocks [0, 3*B*N): row softmin, one row each
// blocks [3*B*N, 3*B*N + B*64*RB): column-softmin partials of C_xy
__global__ __launch_bounds__(256) void k_iter(float* __restrict__ ws, int r) {
    int mode, cur, nxt; float eps, inv_eps;
    if (!round_cfg(ws, r, mode, eps, inv_eps, cur, nxt)) return;
    float ie2 = inv_eps * LOG2E;
    float epsln2 = eps * LN2;
    float wl2 = W_LOG * LOG2E;

    __shared__ float red[4], red2[4];
    __shared__ float sm[4][64], ss[4][64];

    int bid = blockIdx.x;
    if (bid < 3 * Bq * Nq) {
        // ---- row softmin ----
        int op = bid / (Bq * Nq);
        int rem = bid % (Bq * Nq);
        int b = rem >> 12, n = rem & (Nq - 1);
        const unsigned short* C = (const unsigned short*)(ws + F_C)
                                  + (size_t)op * GSZ + ((size_t)b * Nq + n) * Nq;
        int arr_dual = (op == 0) ? 1 : (op == 1 ? 2 : 3);   // g_ab / f_aa / g_bb
        int arr_out  = (op == 0) ? 0 : arr_dual;            // f_ba / f_aa / g_bb
        const uint4* C4 = reinterpret_cast<const uint4*>(C);   // 8 u16 per granule
        const float4* d4 = reinterpret_cast<const float4*>(
            ws + F_FG + ((size_t)cur * 4 + arr_dual) * (Bq * Nq) + (size_t)b * Nq);

        float vs[16];
        float vmax = -INFINITY;
        #pragma unroll
        for (int k = 0; k < 2; k++) {
            int gi = threadIdx.x + 256 * k;                 // granule: cols [gi*8, gi*8+8)
            uint4 cu = C4[gi];
            float4 h0 = make_float4(0.f, 0.f, 0.f, 0.f), h1 = h0;
            if (mode != 0) { h0 = d4[gi * 2]; h1 = d4[gi * 2 + 1]; }
            float hv[8] = {h0.x, h0.y, h0.z, h0.w, h1.x, h1.y, h1.z, h1.w};
            unsigned int uw[4] = {cu.x, cu.y, cu.z, cu.w};
            #pragma unroll
            for (int j = 0; j < 8; j++) {
                unsigned int u = (uw[j >> 1] >> ((j & 1) * 16)) & 0xffffu;
                float Cv = (float)u * DQ_SCALE;
                float v = (hv[j] - Cv) * ie2;               // log2 domain, W folded at end
                vs[k * 8 + j] = v;
                vmax = fmaxf(vmax, v);
            }
        }
        #pragma unroll
        for (int o = 32; o > 0; o >>= 1) vmax = fmaxf(vmax, __shfl_xor(vmax, o));
        int wid = threadIdx.x >> 6;
        if ((threadIdx.x & 63) == 0) red[wid] = vmax;
        __syncthreads();
        float bm = fmaxf(fmaxf(red[0], red[1]), fmaxf(red[2], red[3]));
        float s = 0.f;
        #pragma unroll
        for (int k = 0; k < 16; k++) s += exp2f(vs[k] - bm);
        #pragma unroll
        for (int o = 32; o > 0; o >>= 1) s += __shfl_xor(s, o);
        if ((threadIdx.x & 63) == 0) red2[wid] = s;
        __syncthreads();
        if (threadIdx.x == 0) {
            float st = red2[0] + red2[1] + red2[2] + red2[3];
            float ft = -epsln2 * (wl2 + bm + log2f(st));
            float* outp = ws + F_FG + ((size_t)nxt * 4 + arr_out) * (Bq * Nq) + (size_t)b * Nq;
            const float* oldp = ws + F_FG + ((size_t)cur * 4 + arr_out) * (Bq * Nq) + (size_t)b * Nq;
            outp[n] = (mode == 1) ? 0.5f * (oldp[n] + ft) : ft;
        }
    } else {
        // ---- column partials over C_xy ----
        int cid = bid - 3 * Bq * Nq;          // B * 64 colblocks * RB bands
        int band = cid & (RB - 1);
        int cb = (cid >> 3) & 63;
        int b = cid >> 9;
        int c = threadIdx.x & 63, q = threadIdx.x >> 6;
        int m = cb * 64 + c;
        const unsigned short* C = (const unsigned short*)(ws + F_C) + (size_t)b * Nq * Nq; // C_xy
        const float* fba = ws + F_FG + ((size_t)cur * 4 + 0) * (Bq * Nq) + (size_t)b * Nq;

        float mx = -INFINITY, s = 0.f;
        int n0 = band * (Nq / RB);
        for (int n = n0 + q; n < n0 + Nq / RB; n += 4) {
            float Cv = (float)C[(size_t)n * Nq + m] * DQ_SCALE;
            float h = (mode == 0) ? 0.f : fba[n];            // wave-uniform -> scalar load
            float v = (h - Cv) * ie2;
            float nm = fmaxf(mx, v);
            s = s * exp2f(mx - nm) + exp2f(v - nm);
            mx = nm;
        }
        sm[q][c] = mx; ss[q][c] = s;
        __syncthreads();
        if (threadIdx.x < 64) {
            float M = fmaxf(fmaxf(sm[0][c], sm[1][c]), fmaxf(sm[2][c], sm[3][c]));
            float S = ss[0][c] * exp2f(sm[0][c] - M) + ss[1][c] * exp2f(sm[1][c] - M)
                    + ss[2][c] * exp2f(sm[2][c] - M) + ss[3][c] * exp2f(sm[3][c] - M);
            size_t o = F_CP + (((size_t)b * Nq + cb * 64 + c) * RB + band) * 2;
            ws[o] = M; ws[o + 1] = S;
        }
    }
}

__global__ __launch_bounds__(256) void k_colcomb(float* __restrict__ ws, int r) {
    int mode, cur, nxt; float eps, inv_eps;
    if (!round_cfg(ws, r, mode, eps, inv_eps, cur, nxt)) return;
    float epsln2 = eps * LN2;
    float wl2 = W_LOG * LOG2E;
    int idx = blockIdx.x * 256 + threadIdx.x;
    if (idx >= Bq * Nq) return;
    int b = idx >> 12, m = idx & (Nq - 1);
    size_t o = F_CP + (((size_t)b * Nq + m) * RB) * 2;
    float M = -INFINITY;
    #pragma unroll
    for (int k = 0; k < RB; k++) M = fmaxf(M, ws[o + 2 * k]);
    float S = 0.f;
    #pragma unroll
    for (int k = 0; k < RB; k++) S += ws[o + 2 * k + 1] * exp2f(ws[o + 2 * k] - M);
    float gt = -epsln2 * (wl2 + M + log2f(S));
    float* outp = ws + F_FG + ((size_t)nxt * 4 + 1) * (Bq * Nq) + (size_t)b * Nq;
    const float* oldp = ws + F_FG + ((size_t)cur * 4 + 1) * (Bq * Nq) + (size_t)b * Nq;
    outp[m] = (mode == 1) ? 0.5f * (oldp[m] + gt) : gt;
}

// ---------------- fallback: fused recompute + row softmin (small ws) ----------------
__global__ __launch_bounds__(256) void k_fused(float* __restrict__ ws, int r) {
    int mode, cur, nxt; float eps, inv_eps;
    if (!round_cfg(ws, r, mode, eps, inv_eps, cur, nxt)) return;
    int op = blockIdx.z, b = blockIdx.y;
    int tr = blockIdx.x * 64;
    const float* A  = ws + ((op == 1 || op == 3) ? F_YN : F_XN) + (size_t)b * Nq * Dq;
    const float* Bp = ws + ((op == 0 || op == 3) ? F_YN : F_XN) + (size_t)b * Nq * Dq;
    int dual_arr = (op == 0) ? 1 : (op == 1) ? 0 : (op == 2) ? 2 : 3;
    int out_arr  = (op == 0) ? 0 : (op == 1) ? 1 : (op == 2) ? 2 : 3;
    const float* hdual = ws + F_FG + ((size_t)cur * 4 + dual_arr) * (Bq * Nq) + (size_t)b * Nq;

    __shared__ float As[64][65], Bs[64][65];
    #pragma unroll
    for (int i = 0; i < 16; i++) {
        int idx = threadIdx.x + 256 * i;
        As[idx >> 6][idx & 63] = A[(size_t)(tr + (idx >> 6)) * Dq + (idx & 63)];
    }
    int tx = threadIdx.x & 15, ty = threadIdx.x >> 4;
    float m_i[4], s_i[4];
    #pragma unroll
    for (int i = 0; i < 4; i++) { m_i[i] = -INFINITY; s_i[i] = 0.f; }

    for (int tc = 0; tc < Nq; tc += 64) {
        __syncthreads();
        #pragma unroll
        for (int i = 0; i < 16; i++) {
            int idx = threadIdx.x + 256 * i;
            Bs[idx >> 6][idx & 63] = Bp[(size_t)(tc + (idx >> 6)) * Dq + (idx & 63)];
        }
        __syncthreads();
        float acc[4][4] = {};
        #pragma unroll
        for (int dd = 0; dd < 64; dd++) {
            float a[4], bb[4];
            #pragma unroll
            for (int i = 0; i < 4; i++) a[i] = As[ty * 4 + i][dd];
            #pragma unroll
            for (int j = 0; j < 4; j++) bb[j] = Bs[tx * 4 + j][dd];
            #pragma unroll
            for (int i = 0; i < 4; i++)
                #pragma unroll
                for (int j = 0; j < 4; j++) acc[i][j] = fmaf(a[i], bb[j], acc[i][j]);
        }
        float hv[4];
        #pragma unroll
        for (int j = 0; j < 4; j++)
            hv[j] = (mode == 0) ? 0.f : hdual[tc + tx * 4 + j];
        #pragma unroll
        for (int i = 0; i < 4; i++) {
            float v[4], tm = -INFINITY;
            #pragma unroll
            for (int j = 0; j < 4; j++) {
                float c = 1.0f - acc[i][j];
                v[j] = W_LOG + (hv[j] - c * c) * inv_eps;
                tm = fmaxf(tm, v[j]);
            }
            float nm = fmaxf(m_i[i], tm);
            float add = 0.f;
            #pragma unroll
            for (int j = 0; j < 4; j++) add += expf(v[j] - nm);
            s_i[i] = s_i[i] * expf(m_i[i] - nm) + add;
            m_i[i] = nm;
        }
    }
    #pragma unroll
    for (int o = 1; o < 16; o <<= 1) {
        #pragma unroll
        for (int i = 0; i < 4; i++) {
            float om = __shfl_xor(m_i[i], o);
            float os = __shfl_xor(s_i[i], o);
            float M = fmaxf(m_i[i], om);
            s_i[i] = s_i[i] * expf(m_i[i] - M) + os * expf(om - M);
            m_i[i] = M;
        }
    }
    if (tx == 0) {
        float* outp = ws + F_FG + ((size_t)nxt * 4 + out_arr) * (Bq * Nq) + (size_t)b * Nq;
        const float* oldp = ws + F_FG + ((size_t)cur * 4 + out_arr) * (Bq * Nq) + (size_t)b * Nq;
        #pragma unroll
        for (int i = 0; i < 4; i++) {
            int n = tr + ty * 4 + i;
            float ft = -eps * (m_i[i] + logf(s_i[i]));
            outp[n] = (mode == 1) ? 0.5f * (oldp[n] + ft) : ft;
        }
    }
}

// ---------------- final cost ----------------
__global__ __launch_bounds__(256) void k_final(const float* __restrict__ ws,
                                               float* __restrict__ out) {
    const int* ei = (const int*)(ws + F_EPS);
    int n_eps = ei[0];
    int fin = n_eps & 1;                  // copy written by round n_eps+1
    int b = blockIdx.x;
    const float* fba = ws + F_FG + ((size_t)fin * 4 + 0) * (Bq * Nq) + (size_t)b * Nq;
    const float* gab = ws + F_FG + ((size_t)fin * 4 + 1) * (Bq * Nq) + (size_t)b * Nq;
    const float* faa = ws + F_FG + ((size_t)fin * 4 + 2) * (Bq * Nq) + (size_t)b * Nq;
    const float* gbb = ws + F_FG + ((size_t)fin * 4 + 3) * (Bq * Nq) + (size_t)b * Nq;
    float s = 0.f;
    for (int n = threadIdx.x; n < Nq; n += 256)
        s += (fba[n] - faa[n]) + (gab[n] - gbb[n]);
    #pragma unroll
    for (int o = 32; o > 0; o >>= 1) s += __shfl_xor(s, o);
    __shared__ float red[4];
    if ((threadIdx.x & 63) == 0) red[threadIdx.x >> 6] = s;
    __syncthreads();
    if (threadIdx.x == 0)
        out[b] = (red[0] + red[1] + red[2] + red[3]) * (1.0f / Nq);
}

// sentinel: ws too small even for the fallback
__global__ void k_sentinel(float* out, int n) {
    if ((int)threadIdx.x < n) out[threadIdx.x] = 2.0e9f;
}

extern "C" void kernel_launch(void* const* d_in, const int* in_sizes, int n_in,
                              void* d_out, int out_size, void* d_ws, size_t ws_size,
                              hipStream_t stream) {
    const float* x = (const float*)d_in[0];
    const float* y = (const float*)d_in[1];
    float* out = (float*)d_out;
    float* ws = (float*)d_ws;

    bool big   = ws_size >= F_TOTAL_P * sizeof(float);   // ~210 MB
    bool small = ws_size >= F_TOTAL_S * sizeof(float);   // ~9.5 MB fallback footprint

    if (!small) {
        k_sentinel<<<1, 64, 0, stream>>>(out, out_size);
        return;
    }

    k_normalize<<<(2 * Bq * Nq * 64) / 256, 256, 0, stream>>>(x, y, ws);
    k_minmax<<<64, 256, 0, stream>>>(x, y, ws);
    k_eps<<<1, 64, 0, stream>>>(ws);

    if (big) {
        k_gram_mfma<<<dim3(4096, Bq, 3), 256, 0, stream>>>(ws);
        for (int r = 0; r < MAXR; r++) {
            k_iter<<<3 * Bq * Nq + Bq * 64 * RB, 256, 0, stream>>>(ws, r);
            k_colcomb<<<(Bq * Nq + 255) / 256, 256, 0, stream>>>(ws, r);
        }
    } else {
        for (int r = 0; r < MAXR; r++) {
            k_fused<<<dim3(Nq / 64, Bq, 4), 256, 0, stream>>>(ws, r);
        }
    }

    k_final<<<Bq, 256, 0, stream>>>(ws, out);
}